// Round 4
// baseline (66.344 us; speedup 1.0000x reference)
//
#include <hip/hip_runtime.h>
#include <math.h>

#define BB 256
#define LL 8
#define DD 200
#define NN 100000
#define KP 224                       // K padded to 14*16
#define NGRAN 28                     // 16B granules (8 bf16) per row
#define BN 64                        // concepts per tile/block
#define NT ((NN + BN - 1) / BN)      // 1563 tiles = grid
#define NCAND 6

typedef __attribute__((ext_vector_type(8))) __bf16 bf16x8;
typedef __attribute__((ext_vector_type(16))) float f32x16;

// fp32 -> bf16 round-to-nearest-even
__device__ __forceinline__ unsigned f2bf(float x) {
  unsigned u = __float_as_uint(x);
  u = (u + 0x7fffu + ((u >> 16) & 1u)) >> 16;
  return u;
}
__device__ __forceinline__ unsigned pk(float a, float b) {
  return f2bf(a) | (f2bf(b) << 16);
}
// numpy argmax semantics: larger wins; exact tie -> smaller index
__device__ __forceinline__ bool better(float a, int ia, float b, int ib) {
  return (a > b) || (a == b && ia < ib);
}

// ---------------- Phase 1: mention rep (fp32 + bf16 granule-major) ----------
// abfT layout: uint4 index g*256 + m  (granule-major -> coalesced wave loads)
__global__ __launch_bounds__(256) void prep_kernel(
    const int* __restrict__ ids, const float* __restrict__ we,
    float* __restrict__ repf, unsigned short* __restrict__ abf,
    float* __restrict__ mnorm) {
  int m = blockIdx.x, d = threadIdx.x;
  __shared__ float red[4];
  float r = 0.f;
  if (d < DD) {
    int base = m * LL;
#pragma unroll
    for (int l2 = 0; l2 < LL; ++l2) r += we[(size_t)ids[base + l2] * DD + d];
    r *= 0.125f;
    repf[m * DD + d] = r;
  }
  if (d < KP) {
    int g = d >> 3, wo = d & 7;
    abf[(g * 256 + m) * 8 + wo] = (unsigned short)f2bf(d < DD ? r : 0.f);
  }
  float sq = (d < DD) ? r * r : 0.f;
#pragma unroll
  for (int off = 32; off; off >>= 1) sq += __shfl_down(sq, off);
  if ((threadIdx.x & 63) == 0) red[threadIdx.x >> 6] = sq;
  __syncthreads();
  if (threadIdx.x == 0) mnorm[m] = sqrtf(red[0] + red[1] + red[2] + red[3]);
}

// ---------------- Phase 2: one 64-concept tile per block ---------------------
__global__ __launch_bounds__(1024, 8) void sim_kernel(
    const float* __restrict__ dict, const uint4* __restrict__ abfT,
    float4* __restrict__ partial) {
  __shared__ uint4 Bs[NGRAN * 64];     // 28KB dict tile, bf16 swizzled
  __shared__ float rcn_s[BN];
  __shared__ float4 red_s[BB][2];      // 8KB cross-wave merge

  int t = blockIdx.x;
  int n0 = t * BN;
  int tid = threadIdx.x;

  // ---- stage: 64 rows x 16 parts; issue all global loads, then cvt+store ----
  {
    int row = tid >> 4, part = tid & 15;
    int n = n0 + row;
    bool ok = (n < NN);
    float sc = ok ? 1.f : 0.f;
    const float* src = dict + (size_t)(ok ? n : 0) * DD;
    float4 f0 = *(const float4*)(src + part * 8);
    float4 f1 = *(const float4*)(src + part * 8 + 4);
    float4 g0 = make_float4(0.f, 0.f, 0.f, 0.f), g1 = g0;
    if (part <= 8) {   // granules 16..24 hold k 128..199
      g0 = *(const float4*)(src + (part + 16) * 8);
      g1 = *(const float4*)(src + (part + 16) * 8 + 4);
    }
    float sq = 0.f;
    {
      float a = f0.x * sc, b = f0.y * sc, c = f0.z * sc, d2 = f0.w * sc;
      float e = f1.x * sc, h = f1.y * sc, p = f1.z * sc, q = f1.w * sc;
      sq += a * a + b * b + c * c + d2 * d2 + e * e + h * h + p * p + q * q;
      uint4 u; u.x = pk(a, b); u.y = pk(c, d2); u.z = pk(e, h); u.w = pk(p, q);
      Bs[part * 64 + (row ^ ((2 * part) & 7))] = u;
    }
    if (part <= 11) {  // granules 16..27 (25..27 are zero pad)
      int g = part + 16;
      float a = g0.x * sc, b = g0.y * sc, c = g0.z * sc, d2 = g0.w * sc;
      float e = g1.x * sc, h = g1.y * sc, p = g1.z * sc, q = g1.w * sc;
      sq += a * a + b * b + c * c + d2 * d2 + e * e + h * h + p * p + q * q;
      uint4 u; u.x = pk(a, b); u.y = pk(c, d2); u.z = pk(e, h); u.w = pk(p, q);
      Bs[g * 64 + (row ^ ((2 * g) & 7))] = u;
    }
    sq += __shfl_xor(sq, 1); sq += __shfl_xor(sq, 2);
    sq += __shfl_xor(sq, 4); sq += __shfl_xor(sq, 8);
    if (part == 0) rcn_s[row] = 1.0f / fmaxf(sqrtf(sq), 1e-8f);
  }

  int w = tid >> 6, l = tid & 63, ln = l & 31, kh = l >> 5;
  int mg = w >> 1, nh = w & 1;         // 8 m-groups x 2 n-halves
  int m = mg * 32 + ln;

  f32x16 acc;
#pragma unroll
  for (int i = 0; i < 16; ++i) acc[i] = 0.f;

  __syncthreads();

  // ---- 14 MFMA: dict rows (A) from LDS, mention cols (B) streamed from L2 ----
#pragma unroll
  for (int j = 0; j < 14; ++j) {
    int g = 2 * j + kh;
    uint4 a = abfT[g * 256 + m];       // coalesced 512B per wave-half
    bf16x8 db = __builtin_bit_cast(bf16x8, Bs[g * 64 + ((nh * 32 + ln) ^ ((2 * g) & 7))]);
    acc = __builtin_amdgcn_mfma_f32_32x32x16_bf16(db, __builtin_bit_cast(bf16x8, a), acc, 0, 0, 0);
  }

  // ---- lane-local top-2 over 16 n-values (n monotone -> smaller-idx ties) ----
  float v1 = -INFINITY, v2 = -INFINITY;
  int i1 = 0x7fffffff, i2 = 0x7fffffff;
#pragma unroll
  for (int r = 0; r < 16; ++r) {
    int nl = nh * 32 + (r & 3) + 8 * (r >> 2) + 4 * kh;
    int n = n0 + nl;
    float v = acc[r] * rcn_s[nl];      // broadcast LDS read
    v = (n < NN) ? v : -INFINITY;
    if (v > v1) { v2 = v1; i2 = i1; v1 = v; i1 = n; }
    else if (v > v2) { v2 = v; i2 = n; }
  }
  // merge the two kh halves (same m, disjoint n)
  float w1 = __shfl_xor(v1, 32); int j1 = __shfl_xor(i1, 32);
  float w2 = __shfl_xor(v2, 32); int j2 = __shfl_xor(i2, 32);
  float o1, o2; int oi1, oi2;
  if (better(w1, j1, v1, i1)) {
    bool tt = better(v1, i1, w2, j2);
    o1 = w1; oi1 = j1; o2 = tt ? v1 : w2; oi2 = tt ? i1 : j2;
  } else {
    bool tt = better(w1, j1, v2, i2);
    o1 = v1; oi1 = i1; o2 = tt ? w1 : v2; oi2 = tt ? j1 : i2;
  }
  if (kh == 0)
    red_s[m][nh] = make_float4(o1, __int_as_float(oi1), o2, __int_as_float(oi2));
  __syncthreads();
  // merge the two n-halves, write per-(m,tile) top-2
  if (tid < BB) {
    float4 e0 = red_s[tid][0], e1 = red_s[tid][1];
    float a1 = e0.x; int c1 = __float_as_int(e0.y);
    float a2 = e0.z; int c2 = __float_as_int(e0.w);
    float b1 = e1.x; int d1 = __float_as_int(e1.y);
    float b2 = e1.z; int d2 = __float_as_int(e1.w);
    float p1, p2; int q1, q2;
    if (better(b1, d1, a1, c1)) {
      bool tt = better(a1, c1, b2, d2);
      p1 = b1; q1 = d1; p2 = tt ? a1 : b2; q2 = tt ? c1 : d2;
    } else {
      bool tt = better(b1, d1, a2, c2);
      p1 = a1; q1 = c1; p2 = tt ? b1 : a2; q2 = tt ? d1 : c2;
    }
    partial[(size_t)tid * NT + t] =
        make_float4(p1, __int_as_float(q1), p2, __int_as_float(q2));
  }
}

// ---------------- Phase 3: top-6 select + exact fp32 rescore -----------------
__global__ __launch_bounds__(256) void final_kernel(
    const float* __restrict__ dict, const float* __restrict__ repf,
    const float* __restrict__ mnorm, const float4* __restrict__ partial,
    float* __restrict__ out) {
  int m = blockIdx.x, tid = threadIdx.x;
  __shared__ float repL[DD];
  __shared__ int seln[NCAND];
  __shared__ float wv[4]; __shared__ int wi[4];
  __shared__ float finv[NCAND]; __shared__ int finn[NCAND];
  if (tid < DD) repL[tid] = repf[m * DD + tid];
  __syncthreads();

  // preload this mention's 1563 tile-entries once into registers
  const float4* pm = partial + (size_t)m * NT;
  float cv1[7], cv2[7]; int ci1[7], ci2[7];
#pragma unroll
  for (int e = 0; e < 7; ++e) {
    int idx = tid + e * 256;
    if (idx < NT) {
      float4 E = pm[idx];
      cv1[e] = E.x; ci1[e] = __float_as_int(E.y);
      cv2[e] = E.z; ci2[e] = __float_as_int(E.w);
    } else {
      cv1[e] = -INFINITY; ci1[e] = 0x7fffffff;
      cv2[e] = -INFINITY; ci2[e] = 0x7fffffff;
    }
  }

  for (int r = 0; r < NCAND; ++r) {
    float bv = -INFINITY; int bi = 0x7fffffff;
#pragma unroll
    for (int e = 0; e < 7; ++e) {
      bool ex1 = false, ex2 = false;
      for (int j = 0; j < r; ++j) {
        int s = seln[j];
        ex1 |= (s == ci1[e]); ex2 |= (s == ci2[e]);
      }
      if (!ex1 && better(cv1[e], ci1[e], bv, bi)) { bv = cv1[e]; bi = ci1[e]; }
      if (!ex2 && better(cv2[e], ci2[e], bv, bi)) { bv = cv2[e]; bi = ci2[e]; }
    }
#pragma unroll
    for (int off = 1; off < 64; off <<= 1) {
      float ov = __shfl_xor(bv, off); int oi = __shfl_xor(bi, off);
      if (better(ov, oi, bv, bi)) { bv = ov; bi = oi; }
    }
    if ((tid & 63) == 0) { wv[tid >> 6] = bv; wi[tid >> 6] = bi; }
    __syncthreads();
    if (tid == 0) {
      float Bv = wv[0]; int Bi = wi[0];
#pragma unroll
      for (int q = 1; q < 4; ++q)
        if (better(wv[q], wi[q], Bv, Bi)) { Bv = wv[q]; Bi = wi[q]; }
      seln[r] = Bi;
    }
    __syncthreads();
  }

  // exact fp32 rescore of the NCAND candidates: one 32-lane group each
  int g = tid >> 5, lane = tid & 31;
  int n = (g < NCAND) ? seln[g] : -1;
  float s1 = 0.f, s2 = 0.f;
  if (n >= 0) {
    for (int d = lane; d < DD; d += 32) {
      float b = dict[(size_t)n * DD + d];
      s1 += repL[d] * b; s2 += b * b;
    }
  }
#pragma unroll
  for (int off = 1; off < 32; off <<= 1) {
    s1 += __shfl_xor(s1, off); s2 += __shfl_xor(s2, off);
  }
  if (lane == 0 && g < NCAND) {
    finv[g] = (n >= 0) ? s1 / fmaxf(mnorm[m] * sqrtf(s2), 1e-8f) : -INFINITY;
    finn[g] = n;
  }
  __syncthreads();
  if (tid == 0) {
    float Bv = finv[0]; int Bi = finn[0];
#pragma unroll
    for (int q = 1; q < NCAND; ++q)
      if (better(finv[q], finn[q], Bv, Bi)) { Bv = finv[q]; Bi = finn[q]; }
    out[m] = Bv;
    out[BB + m] = (float)Bi;  // indices as f32 (flat f32 readback)
  }
}

extern "C" void kernel_launch(void* const* d_in, const int* in_sizes, int n_in,
                              void* d_out, int out_size, void* d_ws, size_t ws_size,
                              hipStream_t stream) {
  const int* ids = (const int*)d_in[0];
  const float* we = (const float*)d_in[1];
  const float* dict = (const float*)d_in[2];
  float* out = (float*)d_out;

  char* ws = (char*)d_ws;
  unsigned short* abf = (unsigned short*)ws;              // 28*256*16 = 114688
  float* repf  = (float*)(ws + 114688);                   // 204800
  float* mnorm = (float*)(ws + 319488);                   // 1024
  float4* partial = (float4*)(ws + 320512);               // 256*1563*16 = 6402048

  prep_kernel<<<BB, 256, 0, stream>>>(ids, we, repf, abf, mnorm);
  sim_kernel<<<NT, 1024, 0, stream>>>(dict, (const uint4*)abf, partial);
  final_kernel<<<BB, 256, 0, stream>>>(dict, repf, mnorm, partial, out);
}

// Round 5
// 56.677 us; speedup vs baseline: 1.1706x; 1.1706x over previous
//
#include <hip/hip_runtime.h>
#include <math.h>

#define BB 256
#define LL 8
#define DD 200
#define NN 100000
#define BN 32                        // concepts per tile (100000 % 32 == 0)
#define NTILE (NN / BN)              // 3125
#define NGRAN 28                     // 16B bf16 granules per row (K padded to 224)
#define UPT (NGRAN * BN)             // 896 uint4 units per tile (14 KB)
#define GRID_SIM 512
#define NCAND 6

typedef __attribute__((ext_vector_type(8))) __bf16 bf16x8;
typedef __attribute__((ext_vector_type(16))) float f32x16;

// fp32 -> bf16 round-to-nearest-even
__device__ __forceinline__ unsigned f2bf(float x) {
  unsigned u = __float_as_uint(x);
  u = (u + 0x7fffu + ((u >> 16) & 1u)) >> 16;
  return u;
}
__device__ __forceinline__ unsigned pk(float a, float b) {
  return f2bf(a) | (f2bf(b) << 16);
}
// numpy argmax semantics: larger wins; exact tie -> smaller index
__device__ __forceinline__ bool better(float a, int ia, float b, int ib) {
  return (a > b) || (a == b && ia < ib);
}

// async global->LDS, 16B per lane, dest = uniform base + lane*16
__device__ __forceinline__ void glds16(const void* g, void* l) {
  __builtin_amdgcn_global_load_lds(
      (const __attribute__((address_space(1))) unsigned int*)g,
      (__attribute__((address_space(3))) unsigned int*)l, 16, 0, 0);
}

// ------------- Kernel 1: convert dict -> normalized bf16, tile-major ---------
// dictbf unit (tile, g, row) at index tile*896 + g*32 + row  (16B units)
__global__ __launch_bounds__(256) void convert_kernel(
    const float* __restrict__ dict, uint4* __restrict__ dictbf) {
  __shared__ uint4 T[UPT];
  int tile = blockIdx.x;
  int tid = threadIdx.x;
  int row = tid >> 3, part = tid & 7;
  const float* src = dict + (size_t)(tile * BN + row) * DD;

  float4 f[8];
  int gl[4] = {part, part + 8, part + 16, 24};
  int ng = (part == 0) ? 4 : 3;
  float sq = 0.f;
#pragma unroll
  for (int i = 0; i < 4; ++i) {
    if (i < ng) {
      int g = gl[i];
      float4 a = *(const float4*)(src + g * 8);
      float4 b = *(const float4*)(src + g * 8 + 4);
      f[2 * i] = a; f[2 * i + 1] = b;
      sq += a.x * a.x + a.y * a.y + a.z * a.z + a.w * a.w;
      sq += b.x * b.x + b.y * b.y + b.z * b.z + b.w * b.w;
    }
  }
  // full row norm across the 8 part-lanes
  sq += __shfl_xor(sq, 1); sq += __shfl_xor(sq, 2); sq += __shfl_xor(sq, 4);
  float rs = 1.0f / fmaxf(sqrtf(sq), 1e-8f);
#pragma unroll
  for (int i = 0; i < 4; ++i) {
    if (i < ng) {
      int g = gl[i];
      float4 a = f[2 * i], b = f[2 * i + 1];
      uint4 u;
      u.x = pk(a.x * rs, a.y * rs); u.y = pk(a.z * rs, a.w * rs);
      u.z = pk(b.x * rs, b.y * rs); u.w = pk(b.z * rs, b.w * rs);
      T[g * BN + row] = u;
    }
  }
  if (part >= 1 && part <= 3)   // zero-pad granules 25..27 (k 200..223)
    T[(24 + part) * BN + row] = make_uint4(0, 0, 0, 0);
  __syncthreads();
  // coalesced tile write: 896 units, 256 threads
  size_t base = (size_t)tile * UPT;
#pragma unroll
  for (int e = 0; e < 4; ++e) {
    int idx = tid + e * 256;
    if (idx < UPT) dictbf[base + idx] = T[idx];
  }
}

// ------------- Kernel 2: mention rep (fp32 + bf16 granule-major) -------------
// abfT layout: uint4 index g*256 + m
__global__ __launch_bounds__(256) void prep_kernel(
    const int* __restrict__ ids, const float* __restrict__ we,
    float* __restrict__ repf, unsigned short* __restrict__ abf,
    float* __restrict__ mnorm) {
  int m = blockIdx.x, d = threadIdx.x;
  __shared__ float red[4];
  float r = 0.f;
  if (d < DD) {
    int base = m * LL;
#pragma unroll
    for (int l2 = 0; l2 < LL; ++l2) r += we[(size_t)ids[base + l2] * DD + d];
    r *= 0.125f;
    repf[m * DD + d] = r;
  }
  if (d < NGRAN * 8) {
    int g = d >> 3, wo = d & 7;
    abf[(g * 256 + m) * 8 + wo] = (unsigned short)f2bf(d < DD ? r : 0.f);
  }
  float sq = (d < DD) ? r * r : 0.f;
#pragma unroll
  for (int off = 32; off; off >>= 1) sq += __shfl_down(sq, off);
  if ((threadIdx.x & 63) == 0) red[threadIdx.x >> 6] = sq;
  __syncthreads();
  if (threadIdx.x == 0) mnorm[m] = sqrtf(red[0] + red[1] + red[2] + red[3]);
}

// ------------- Kernel 3: MFMA sims over normalized dict ---------------------
__global__ __launch_bounds__(512, 4) void sim_kernel(
    const uint4* __restrict__ dictbf, const uint4* __restrict__ abfT,
    float4* __restrict__ partial) {
  __shared__ uint4 Bs[2][UPT];        // 2 x 14 KB ring

  int tid = threadIdx.x;
  int w = tid >> 6, l = tid & 63;
  int ln = l & 31, kh = l >> 5;
  int m = w * 32 + ln;

  // mention fragments resident: granule 2j+kh for k-step j
  uint4 areg[14];
#pragma unroll
  for (int j = 0; j < 14; ++j) areg[j] = abfT[(2 * j + kh) * 256 + m];

  float v1 = -INFINITY, v2 = -INFINITY;
  int i1 = 0x7fffffff, i2 = 0x7fffffff;

  int t0 = blockIdx.x;
  // prologue: stage tile t0 into buf 0 (waves 0..6, 2 issues each)
  if (w < 7) {
#pragma unroll
    for (int i = 0; i < 2; ++i) {
      int u = w * 128 + i * 64;
      glds16(dictbf + (size_t)t0 * UPT + u + l, (char*)&Bs[0][0] + u * 16);
    }
  }

  int cur = 0;
  for (int t = t0; t < NTILE; t += GRID_SIM) {
    int tn = t + GRID_SIM;
    bool hn = tn < NTILE;
    if (hn && w < 7) {
#pragma unroll
      for (int i = 0; i < 2; ++i) {
        int u = w * 128 + i * 64;
        glds16(dictbf + (size_t)tn * UPT + u + l,
               (char*)&Bs[cur ^ 1][0] + u * 16);
      }
    }
    if (hn) asm volatile("s_waitcnt vmcnt(2)" ::: "memory");
    else    asm volatile("s_waitcnt vmcnt(0)" ::: "memory");
    __builtin_amdgcn_s_barrier();
    __builtin_amdgcn_sched_barrier(0);

    f32x16 acc;
#pragma unroll
    for (int i = 0; i < 16; ++i) acc[i] = 0.f;
    const uint4* B = Bs[cur];
#pragma unroll
    for (int j = 0; j < 14; ++j) {
      bf16x8 a = __builtin_bit_cast(bf16x8, B[(2 * j + kh) * 32 + ln]);
      acc = __builtin_amdgcn_mfma_f32_32x32x16_bf16(
          a, __builtin_bit_cast(bf16x8, areg[j]), acc, 0, 0, 0);
    }

    // lane-local running top-2; n scan order monotone -> numpy tie semantics
    int n0 = t * BN + 4 * kh;
#pragma unroll
    for (int r = 0; r < 16; ++r) {
      int n = n0 + (r & 3) + 8 * (r >> 2);
      float v = acc[r];
      if (v > v1) { v2 = v1; i2 = i1; v1 = v; i1 = n; }
      else if (v > v2) { v2 = v; i2 = n; }
    }
    __builtin_amdgcn_s_barrier();   // buf[cur] fully consumed before reuse
    cur ^= 1;
  }

  // merge the two kh halves (same m, disjoint n)
  float w1 = __shfl_xor(v1, 32); int j1 = __shfl_xor(i1, 32);
  float w2 = __shfl_xor(v2, 32); int j2 = __shfl_xor(i2, 32);
  float o1, o2; int oi1, oi2;
  if (better(w1, j1, v1, i1)) {
    bool tt = better(v1, i1, w2, j2);
    o1 = w1; oi1 = j1; o2 = tt ? v1 : w2; oi2 = tt ? i1 : j2;
  } else {
    bool tt = better(w1, j1, v2, i2);
    o1 = v1; oi1 = i1; o2 = tt ? w1 : v2; oi2 = tt ? j1 : i2;
  }
  if (kh == 0)
    partial[(size_t)m * GRID_SIM + blockIdx.x] =
        make_float4(o1, __int_as_float(oi1), o2, __int_as_float(oi2));
}

// ------------- Kernel 4: top-6 select + exact fp32 rescore -------------------
__global__ __launch_bounds__(256) void final_kernel(
    const float* __restrict__ dict, const float* __restrict__ repf,
    const float* __restrict__ mnorm, const float4* __restrict__ partial,
    float* __restrict__ out) {
  int m = blockIdx.x, tid = threadIdx.x;
  __shared__ float repL[DD];
  __shared__ int seln[NCAND];
  __shared__ float wv[4]; __shared__ int wi[4];
  __shared__ float finv[NCAND]; __shared__ int finn[NCAND];
  if (tid < DD) repL[tid] = repf[m * DD + tid];
  __syncthreads();

  const float4* pm = partial + (size_t)m * GRID_SIM;
  float cv1[2], cv2[2]; int ci1[2], ci2[2];
#pragma unroll
  for (int e = 0; e < 2; ++e) {
    float4 E = pm[tid + e * 256];
    cv1[e] = E.x; ci1[e] = __float_as_int(E.y);
    cv2[e] = E.z; ci2[e] = __float_as_int(E.w);
  }

  for (int r = 0; r < NCAND; ++r) {
    float bv = -INFINITY; int bi = 0x7fffffff;
#pragma unroll
    for (int e = 0; e < 2; ++e) {
      bool ex1 = false, ex2 = false;
      for (int j = 0; j < r; ++j) {
        int s = seln[j];
        ex1 |= (s == ci1[e]); ex2 |= (s == ci2[e]);
      }
      if (!ex1 && better(cv1[e], ci1[e], bv, bi)) { bv = cv1[e]; bi = ci1[e]; }
      if (!ex2 && better(cv2[e], ci2[e], bv, bi)) { bv = cv2[e]; bi = ci2[e]; }
    }
#pragma unroll
    for (int off = 1; off < 64; off <<= 1) {
      float ov = __shfl_xor(bv, off); int oi = __shfl_xor(bi, off);
      if (better(ov, oi, bv, bi)) { bv = ov; bi = oi; }
    }
    if ((tid & 63) == 0) { wv[tid >> 6] = bv; wi[tid >> 6] = bi; }
    __syncthreads();
    if (tid == 0) {
      float Bv = wv[0]; int Bi = wi[0];
#pragma unroll
      for (int q = 1; q < 4; ++q)
        if (better(wv[q], wi[q], Bv, Bi)) { Bv = wv[q]; Bi = wi[q]; }
      seln[r] = Bi;
    }
    __syncthreads();
  }

  // exact fp32 rescore: one 32-lane group per candidate
  int g = tid >> 5, lane = tid & 31;
  int n = (g < NCAND) ? seln[g] : -1;
  float s1 = 0.f, s2 = 0.f;
  if (n >= 0) {
    for (int d = lane; d < DD; d += 32) {
      float b = dict[(size_t)n * DD + d];
      s1 += repL[d] * b; s2 += b * b;
    }
  }
#pragma unroll
  for (int off = 1; off < 32; off <<= 1) {
    s1 += __shfl_xor(s1, off); s2 += __shfl_xor(s2, off);
  }
  if (lane == 0 && g < NCAND) {
    finv[g] = (n >= 0) ? s1 / fmaxf(mnorm[m] * sqrtf(s2), 1e-8f) : -INFINITY;
    finn[g] = n;
  }
  __syncthreads();
  if (tid == 0) {
    float Bv = finv[0]; int Bi = finn[0];
#pragma unroll
    for (int q = 1; q < NCAND; ++q)
      if (better(finv[q], finn[q], Bv, Bi)) { Bv = finv[q]; Bi = finn[q]; }
    out[m] = Bv;
    out[BB + m] = (float)Bi;  // indices as f32 (flat f32 readback)
  }
}

extern "C" void kernel_launch(void* const* d_in, const int* in_sizes, int n_in,
                              void* d_out, int out_size, void* d_ws, size_t ws_size,
                              hipStream_t stream) {
  const int* ids = (const int*)d_in[0];
  const float* we = (const float*)d_in[1];
  const float* dict = (const float*)d_in[2];
  float* out = (float*)d_out;

  char* ws = (char*)d_ws;
  uint4* dictbf = (uint4*)ws;                              // 3125*896*16 = 44,800,000
  unsigned short* abf = (unsigned short*)(ws + 44800000);  // 114,688
  float* repf  = (float*)(ws + 44914688);                  // 204,800
  float* mnorm = (float*)(ws + 45119488);                  // 1,024
  float4* partial = (float4*)(ws + 45120512);              // 256*512*16 = 2,097,152

  convert_kernel<<<NTILE, 256, 0, stream>>>(dict, dictbf);
  prep_kernel<<<BB, 256, 0, stream>>>(ids, we, repf, abf, mnorm);
  sim_kernel<<<GRID_SIM, 512, 0, stream>>>(dictbf, (const uint4*)abf, partial);
  final_kernel<<<BB, 256, 0, stream>>>(dict, repf, mnorm, partial, out);
}

// Round 6
// 45.674 us; speedup vs baseline: 1.4526x; 1.2409x over previous
//
#include <hip/hip_runtime.h>
#include <math.h>

#define BB 256
#define LL 8
#define DD 200
#define NN 100000
#define BN 32                        // concepts per tile (100000 % 32 == 0)
#define NTILE (NN / BN)              // 3125
#define NGRAN 28                     // 16B bf16 granules per row (K padded to 224)
#define GRID_SIM 512
#define NCAND 6

typedef __attribute__((ext_vector_type(8))) __bf16 bf16x8;
typedef __attribute__((ext_vector_type(16))) float f32x16;

// fp32 -> bf16 round-to-nearest-even
__device__ __forceinline__ unsigned f2bf(float x) {
  unsigned u = __float_as_uint(x);
  u = (u + 0x7fffu + ((u >> 16) & 1u)) >> 16;
  return u;
}
__device__ __forceinline__ unsigned pk(float a, float b) {
  return f2bf(a) | (f2bf(b) << 16);
}
// numpy argmax semantics: larger wins; exact tie -> smaller index
__device__ __forceinline__ bool better(float a, int ia, float b, int ib) {
  return (a > b) || (a == b && ia < ib);
}
__device__ __forceinline__ float dot4(float4 f) {
  return f.x * f.x + f.y * f.y + f.z * f.z + f.w * f.w;
}

// ------------- Kernel 1: mention rep (fp32 + bf16 granule-major) -------------
// abfT layout: uint4 unit index g*256 + m
__global__ __launch_bounds__(256) void prep_kernel(
    const int* __restrict__ ids, const float* __restrict__ we,
    float* __restrict__ repf, unsigned short* __restrict__ abf,
    float* __restrict__ mnorm) {
  int m = blockIdx.x, d = threadIdx.x;
  __shared__ float red[4];
  float r = 0.f;
  if (d < DD) {
    int base = m * LL;
#pragma unroll
    for (int l2 = 0; l2 < LL; ++l2) r += we[(size_t)ids[base + l2] * DD + d];
    r *= 0.125f;
    repf[m * DD + d] = r;
  }
  if (d < NGRAN * 8) {
    int g = d >> 3, wo = d & 7;
    abf[(g * 256 + m) * 8 + wo] = (unsigned short)f2bf(d < DD ? r : 0.f);
  }
  float sq = (d < DD) ? r * r : 0.f;
#pragma unroll
  for (int off = 32; off; off >>= 1) sq += __shfl_down(sq, off);
  if ((threadIdx.x & 63) == 0) red[threadIdx.x >> 6] = sq;
  __syncthreads();
  if (threadIdx.x == 0) mnorm[m] = sqrtf(red[0] + red[1] + red[2] + red[3]);
}

// ------------- Kernel 2: fused convert+MFMA sims -----------------------------
// Each block owns tiles t ≡ blockIdx (mod GRID_SIM): reads raw f32 dict rows,
// normalizes, converts to bf16 into LDS (swizzled), MFMAs vs register-resident
// mention fragments, keeps lane-local top-2. One __syncthreads per tile.
__global__ __launch_bounds__(512, 4) void sim_kernel(
    const float* __restrict__ dict, const uint4* __restrict__ abfT,
    float4* __restrict__ partial) {
  __shared__ uint4 Bs[2][NGRAN * BN];   // 2 x 14 KB ring

  int tid = threadIdx.x;
  int w = tid >> 6, l = tid & 63;
  int ln = l & 31, kh = l >> 5;
  int m = w * 32 + ln;

  // mention fragments resident: granule 2j+kh for k-step j
  uint4 areg[14];
#pragma unroll
  for (int j = 0; j < 14; ++j) areg[j] = abfT[(2 * j + kh) * 256 + m];

  // staging role: 32 rows x 16 parts; part p owns float4s {p, p+16, p+32} (+48+p if p<2)
  int row = tid >> 4, part = tid & 15;
  const bool extra = (part < 2);
  int g0i = part >> 1, h = part & 1;    // granules g0i, 8+g0i, 16+g0i (half h), 24 (half part)

  // zero-pad granules 25..27 (k 200..223) once, both buffers
  if (tid < 192) {
    int buf = tid / 96, u = tid % 96;
    int g = 25 + u / 32, r = u & 31;
    Bs[buf][g * 32 + (r ^ (g & 7))] = make_uint4(0, 0, 0, 0);
  }

  float v1 = -INFINITY, v2 = -INFINITY;
  int i1 = 0x7fffffff, i2 = 0x7fffffff;

  int t0 = blockIdx.x;
  // ---- prologue: stage tile t0 into buf 0 ----
  {
    const float* src = dict + (size_t)(t0 * BN + row) * DD;
    float4 f0 = *(const float4*)(src + 4 * part);
    float4 f1 = *(const float4*)(src + 64 + 4 * part);
    float4 f2 = *(const float4*)(src + 128 + 4 * part);
    float4 f3 = extra ? *(const float4*)(src + 192 + 4 * part)
                      : make_float4(0.f, 0.f, 0.f, 0.f);
    float sq = dot4(f0) + dot4(f1) + dot4(f2) + dot4(f3);
    sq += __shfl_xor(sq, 1); sq += __shfl_xor(sq, 2);
    sq += __shfl_xor(sq, 4); sq += __shfl_xor(sq, 8);
    float rs = 1.0f / fmaxf(sqrtf(sq), 1e-8f);
    uint2* B2 = (uint2*)&Bs[0][0];
    B2[(g0i * 32 + (row ^ (g0i & 7))) * 2 + h] =
        make_uint2(pk(f0.x * rs, f0.y * rs), pk(f0.z * rs, f0.w * rs));
    int ga = 8 + g0i;
    B2[(ga * 32 + (row ^ (ga & 7))) * 2 + h] =
        make_uint2(pk(f1.x * rs, f1.y * rs), pk(f1.z * rs, f1.w * rs));
    int gb = 16 + g0i;
    B2[(gb * 32 + (row ^ (gb & 7))) * 2 + h] =
        make_uint2(pk(f2.x * rs, f2.y * rs), pk(f2.z * rs, f2.w * rs));
    if (extra)
      B2[(24 * 32 + (row ^ 0)) * 2 + part] =
          make_uint2(pk(f3.x * rs, f3.y * rs), pk(f3.z * rs, f3.w * rs));
  }
  __syncthreads();

  int cur = 0;
  for (int t = t0; t < NTILE; t += GRID_SIM) {
    bool hn = (t + GRID_SIM) < NTILE;
    float4 f0, f1, f2, f3;
    if (hn) {  // issue next tile's global loads early (hide under MFMA+scan)
      const float* src = dict + (size_t)((t + GRID_SIM) * BN + row) * DD;
      f0 = *(const float4*)(src + 4 * part);
      f1 = *(const float4*)(src + 64 + 4 * part);
      f2 = *(const float4*)(src + 128 + 4 * part);
      f3 = extra ? *(const float4*)(src + 192 + 4 * part)
                 : make_float4(0.f, 0.f, 0.f, 0.f);
    }
    __builtin_amdgcn_sched_barrier(0);   // keep loads issued here (no sinking)

    f32x16 acc;
#pragma unroll
    for (int i = 0; i < 16; ++i) acc[i] = 0.f;
    const uint4* B = Bs[cur];
#pragma unroll
    for (int j = 0; j < 14; ++j) {
      int g = 2 * j + kh;
      bf16x8 a = __builtin_bit_cast(bf16x8, B[g * 32 + (ln ^ (g & 7))]);
      acc = __builtin_amdgcn_mfma_f32_32x32x16_bf16(
          a, __builtin_bit_cast(bf16x8, areg[j]), acc, 0, 0, 0);
    }

    // lane-local running top-2; n scan order monotone -> numpy tie semantics
    int n0 = t * BN + 4 * kh;
#pragma unroll
    for (int r = 0; r < 16; ++r) {
      int n = n0 + (r & 3) + 8 * (r >> 2);
      float v = acc[r];
      if (v > v1) { v2 = v1; i2 = i1; v1 = v; i1 = n; }
      else if (v > v2) { v2 = v; i2 = n; }
    }

    if (hn) {  // convert + write next buffer (other waves no longer read it)
      float sq = dot4(f0) + dot4(f1) + dot4(f2) + dot4(f3);
      sq += __shfl_xor(sq, 1); sq += __shfl_xor(sq, 2);
      sq += __shfl_xor(sq, 4); sq += __shfl_xor(sq, 8);
      float rs = 1.0f / fmaxf(sqrtf(sq), 1e-8f);
      uint2* B2 = (uint2*)&Bs[cur ^ 1][0];
      B2[(g0i * 32 + (row ^ (g0i & 7))) * 2 + h] =
          make_uint2(pk(f0.x * rs, f0.y * rs), pk(f0.z * rs, f0.w * rs));
      int ga = 8 + g0i;
      B2[(ga * 32 + (row ^ (ga & 7))) * 2 + h] =
          make_uint2(pk(f1.x * rs, f1.y * rs), pk(f1.z * rs, f1.w * rs));
      int gb = 16 + g0i;
      B2[(gb * 32 + (row ^ (gb & 7))) * 2 + h] =
          make_uint2(pk(f2.x * rs, f2.y * rs), pk(f2.z * rs, f2.w * rs));
      if (extra)
        B2[(24 * 32 + row) * 2 + part] =
            make_uint2(pk(f3.x * rs, f3.y * rs), pk(f3.z * rs, f3.w * rs));
    }
    __syncthreads();   // publish writes; no vmem in flight here (drain free)
    cur ^= 1;
  }

  // merge the two kh halves (same m, disjoint n)
  float w1 = __shfl_xor(v1, 32); int j1 = __shfl_xor(i1, 32);
  float w2 = __shfl_xor(v2, 32); int j2 = __shfl_xor(i2, 32);
  float o1, o2; int oi1, oi2;
  if (better(w1, j1, v1, i1)) {
    bool tt = better(v1, i1, w2, j2);
    o1 = w1; oi1 = j1; o2 = tt ? v1 : w2; oi2 = tt ? i1 : j2;
  } else {
    bool tt = better(w1, j1, v2, i2);
    o1 = v1; oi1 = i1; o2 = tt ? w1 : v2; oi2 = tt ? j1 : i2;
  }
  if (kh == 0)
    partial[(size_t)m * GRID_SIM + blockIdx.x] =
        make_float4(o1, __int_as_float(oi1), o2, __int_as_float(oi2));
}

// ------------- Kernel 3: top-6 select + exact fp32 rescore -------------------
__global__ __launch_bounds__(256) void final_kernel(
    const float* __restrict__ dict, const float* __restrict__ repf,
    const float* __restrict__ mnorm, const float4* __restrict__ partial,
    float* __restrict__ out) {
  int m = blockIdx.x, tid = threadIdx.x;
  __shared__ float repL[DD];
  __shared__ int seln[NCAND];
  __shared__ float wv[4]; __shared__ int wi[4];
  __shared__ float finv[NCAND]; __shared__ int finn[NCAND];
  if (tid < DD) repL[tid] = repf[m * DD + tid];
  __syncthreads();

  const float4* pm = partial + (size_t)m * GRID_SIM;
  float cv1[2], cv2[2]; int ci1[2], ci2[2];
#pragma unroll
  for (int e = 0; e < 2; ++e) {
    float4 E = pm[tid + e * 256];
    cv1[e] = E.x; ci1[e] = __float_as_int(E.y);
    cv2[e] = E.z; ci2[e] = __float_as_int(E.w);
  }

  for (int r = 0; r < NCAND; ++r) {
    float bv = -INFINITY; int bi = 0x7fffffff;
#pragma unroll
    for (int e = 0; e < 2; ++e) {
      bool ex1 = false, ex2 = false;
      for (int j = 0; j < r; ++j) {
        int s = seln[j];
        ex1 |= (s == ci1[e]); ex2 |= (s == ci2[e]);
      }
      if (!ex1 && better(cv1[e], ci1[e], bv, bi)) { bv = cv1[e]; bi = ci1[e]; }
      if (!ex2 && better(cv2[e], ci2[e], bv, bi)) { bv = cv2[e]; bi = ci2[e]; }
    }
#pragma unroll
    for (int off = 1; off < 64; off <<= 1) {
      float ov = __shfl_xor(bv, off); int oi = __shfl_xor(bi, off);
      if (better(ov, oi, bv, bi)) { bv = ov; bi = oi; }
    }
    if ((tid & 63) == 0) { wv[tid >> 6] = bv; wi[tid >> 6] = bi; }
    __syncthreads();
    if (tid == 0) {
      float Bv = wv[0]; int Bi = wi[0];
#pragma unroll
      for (int q = 1; q < 4; ++q)
        if (better(wv[q], wi[q], Bv, Bi)) { Bv = wv[q]; Bi = wi[q]; }
      seln[r] = Bi;
    }
    __syncthreads();
  }

  // exact fp32 rescore: one 32-lane group per candidate
  int g = tid >> 5, lane = tid & 31;
  int n = (g < NCAND) ? seln[g] : -1;
  float s1 = 0.f, s2 = 0.f;
  if (n >= 0) {
    for (int d = lane; d < DD; d += 32) {
      float b = dict[(size_t)n * DD + d];
      s1 += repL[d] * b; s2 += b * b;
    }
  }
#pragma unroll
  for (int off = 1; off < 32; off <<= 1) {
    s1 += __shfl_xor(s1, off); s2 += __shfl_xor(s2, off);
  }
  if (lane == 0 && g < NCAND) {
    finv[g] = (n >= 0) ? s1 / fmaxf(mnorm[m] * sqrtf(s2), 1e-8f) : -INFINITY;
    finn[g] = n;
  }
  __syncthreads();
  if (tid == 0) {
    float Bv = finv[0]; int Bi = finn[0];
#pragma unroll
    for (int q = 1; q < NCAND; ++q)
      if (better(finv[q], finn[q], Bv, Bi)) { Bv = finv[q]; Bi = finn[q]; }
    out[m] = Bv;
    out[BB + m] = (float)Bi;  // indices as f32 (flat f32 readback)
  }
}

extern "C" void kernel_launch(void* const* d_in, const int* in_sizes, int n_in,
                              void* d_out, int out_size, void* d_ws, size_t ws_size,
                              hipStream_t stream) {
  const int* ids = (const int*)d_in[0];
  const float* we = (const float*)d_in[1];
  const float* dict = (const float*)d_in[2];
  float* out = (float*)d_out;

  char* ws = (char*)d_ws;
  unsigned short* abf = (unsigned short*)ws;              // 28*256*16 = 114,688
  float* repf  = (float*)(ws + 114688);                   // 204,800
  float* mnorm = (float*)(ws + 319488);                   // 1,024
  float4* partial = (float4*)(ws + 320512);               // 256*512*16 = 2,097,152

  prep_kernel<<<BB, 256, 0, stream>>>(ids, we, repf, abf, mnorm);
  sim_kernel<<<GRID_SIM, 512, 0, stream>>>(dict, (const uint4*)abf, partial);
  final_kernel<<<BB, 256, 0, stream>>>(dict, repf, mnorm, partial, out);
}